// Round 1
// baseline (5884.743 us; speedup 1.0000x reference)
//
#include <hip/hip_runtime.h>
#include <hip/hip_bf16.h>

// Problem constants (from reference)
#define Nn   40000
#define Ee   640000
#define Gg   64
#define INF  128
#define Hh   256
#define OUTF 128

// ---------------- degree / norm ----------------
__global__ __launch_bounds__(256) void k_init_deg(float* deg) {
    int i = blockIdx.x * 256 + threadIdx.x;
    if (i < Nn) deg[i] = 1.0f;
}

__global__ __launch_bounds__(256) void k_deg(const int* __restrict__ dst, float* deg) {
    int e = blockIdx.x * 256 + threadIdx.x;
    if (e < Ee) unsafeAtomicAdd(&deg[dst[e]], 1.0f);
}

__global__ __launch_bounds__(256) void k_rsqrt(float* deg) {
    int i = blockIdx.x * 256 + threadIdx.x;
    if (i < Nn) deg[i] = rsqrtf(deg[i]);
}

__global__ __launch_bounds__(256) void k_norm(const int* __restrict__ src, const int* __restrict__ dst,
                                              const float* __restrict__ dis, float* __restrict__ norm) {
    int e = blockIdx.x * 256 + threadIdx.x;
    if (e < Ee) norm[e] = dis[src[e]] * dis[dst[e]];
}

// ---------------- fp32 tiled GEMM: C[M,N] = A[M,K] @ B[K,N] ----------------
// 64x64 tile, 256 threads, 4x4 micro-tile, BK=16. M%64==0, N%64==0, K%16==0.
__global__ __launch_bounds__(256)
void k_gemm(const float* __restrict__ A, const float* __restrict__ B,
            float* __restrict__ C, int M, int N, int K) {
    __shared__ float As[16][68];   // transposed A tile, pad 68 -> 16B-aligned rows, 2-way banks (free)
    __shared__ float Bs[16][68];
    const int tid = threadIdx.x;
    const int tx = tid & 15, ty = tid >> 4;
    const int tx4 = tx * 4, ty4 = ty * 4;
    const int rowBase = blockIdx.x * 64;
    const int colBase = blockIdx.y * 64;

    const int arow = tid >> 2;        // 0..63
    const int akc  = (tid & 3) * 4;   // 0,4,8,12
    const int brow = tid >> 4;        // 0..15
    const int bcol = (tid & 15) * 4;  // 0..60

    float acc[4][4] = {};

    for (int k0 = 0; k0 < K; k0 += 16) {
        float4 av = *(const float4*)&A[(size_t)(rowBase + arow) * K + k0 + akc];
        float4 bv = *(const float4*)&B[(size_t)(k0 + brow) * N + colBase + bcol];
        __syncthreads();
        As[akc + 0][arow] = av.x;
        As[akc + 1][arow] = av.y;
        As[akc + 2][arow] = av.z;
        As[akc + 3][arow] = av.w;
        *(float4*)&Bs[brow][bcol] = bv;
        __syncthreads();
#pragma unroll
        for (int kk = 0; kk < 16; ++kk) {
            float4 a = *(const float4*)&As[kk][ty4];
            float4 b = *(const float4*)&Bs[kk][tx4];
            acc[0][0] += a.x * b.x; acc[0][1] += a.x * b.y; acc[0][2] += a.x * b.z; acc[0][3] += a.x * b.w;
            acc[1][0] += a.y * b.x; acc[1][1] += a.y * b.y; acc[1][2] += a.y * b.z; acc[1][3] += a.y * b.w;
            acc[2][0] += a.z * b.x; acc[2][1] += a.z * b.y; acc[2][2] += a.z * b.z; acc[2][3] += a.z * b.w;
            acc[3][0] += a.w * b.x; acc[3][1] += a.w * b.y; acc[3][2] += a.w * b.z; acc[3][3] += a.w * b.w;
        }
    }
#pragma unroll
    for (int i = 0; i < 4; ++i) {
        float4 r = make_float4(acc[i][0], acc[i][1], acc[i][2], acc[i][3]);
        *(float4*)&C[(size_t)(rowBase + ty4 + i) * N + colBase + tx4] = r;
    }
}

// ---------------- edge scatter: agg[dst] += norm * h[src]  (H = 4<<SH floats) ----------------
template <int SH>
__global__ __launch_bounds__(256)
void k_scatter(const int* __restrict__ src, const int* __restrict__ dst,
               const float* __restrict__ norm, const float* __restrict__ h,
               float* __restrict__ agg) {
    int idx = blockIdx.x * 256 + threadIdx.x;
    const int total = Ee << SH;
    if (idx >= total) return;
    int e = idx >> SH;
    int c = idx & ((1 << SH) - 1);
    int s = src[e];
    int d = dst[e];
    float w = norm[e];
    float4 v = ((const float4*)h)[((size_t)s << SH) + c];
    float* a = &agg[(((size_t)d << SH) + c) * 4];
    unsafeAtomicAdd(a + 0, w * v.x);
    unsafeAtomicAdd(a + 1, w * v.y);
    unsafeAtomicAdd(a + 2, w * v.z);
    unsafeAtomicAdd(a + 3, w * v.w);
}

// ---------------- self-loop + bias (+ReLU): out = agg + dis^2 * h + b ----------------
template <int SH, bool RELU>
__global__ __launch_bounds__(256)
void k_finalize(const float* __restrict__ agg, const float* __restrict__ h,
                const float* __restrict__ dis, const float* __restrict__ bias,
                float* __restrict__ out) {
    int idx = blockIdx.x * 256 + threadIdx.x;
    const int total = Nn << SH;
    if (idx >= total) return;
    int n = idx >> SH;
    int c = idx & ((1 << SH) - 1);
    float s = dis[n];
    s *= s;
    float4 a = ((const float4*)agg)[idx];
    float4 hv = ((const float4*)h)[idx];
    float4 b = ((const float4*)bias)[c];
    float4 r;
    r.x = a.x + s * hv.x + b.x;
    r.y = a.y + s * hv.y + b.y;
    r.z = a.z + s * hv.z + b.z;
    r.w = a.w + s * hv.w + b.w;
    if (RELU) {
        r.x = fmaxf(r.x, 0.0f);
        r.y = fmaxf(r.y, 0.0f);
        r.z = fmaxf(r.z, 0.0f);
        r.w = fmaxf(r.w, 0.0f);
    }
    ((float4*)out)[idx] = r;
}

// ---------------- global mean pool per graph (batch sorted -> binary search, no atomics) ----------------
__global__ __launch_bounds__(128)
void k_pool(const float* __restrict__ emb, const int* __restrict__ batch,
            float* __restrict__ ge) {
    int g = blockIdx.x;   // 0..63
    int f = threadIdx.x;  // 0..127
    int lo = 0, hi = Nn;
    while (lo < hi) { int mid = (lo + hi) >> 1; if (batch[mid] < g) lo = mid + 1; else hi = mid; }
    int start = lo;
    hi = Nn;
    while (lo < hi) { int mid = (lo + hi) >> 1; if (batch[mid] < g + 1) lo = mid + 1; else hi = mid; }
    int end = lo;
    float s = 0.0f;
    for (int n = start; n < end; ++n) s += emb[(size_t)n * OUTF + f];
    float cnt = (float)(end - start);
    ge[g * OUTF + f] = s / fmaxf(cnt, 1.0f);
}

// ---------------- logits: ge[64,128] @ W_cls[128,2] + b_cls ----------------
__global__ __launch_bounds__(128)
void k_logits(const float* __restrict__ ge, const float* __restrict__ Wc,
              const float* __restrict__ bc, float* __restrict__ out) {
    int t = threadIdx.x;  // 0..127
    int g = t >> 1, c = t & 1;
    float s = bc[c];
    for (int k = 0; k < 128; ++k) s += ge[g * 128 + k] * Wc[k * 2 + c];
    out[t] = s;
}

extern "C" void kernel_launch(void* const* d_in, const int* in_sizes, int n_in,
                              void* d_out, int out_size, void* d_ws, size_t ws_size,
                              hipStream_t stream) {
    const float* x     = (const float*)d_in[0];
    const int*   ei    = (const int*)d_in[1];   // row 0: src, row 1: dst
    const int*   batch = (const int*)d_in[2];
    const float* W_in  = (const float*)d_in[3];
    const float* b_in  = (const float*)d_in[4];
    const float* W_mid = (const float*)d_in[5];
    const float* b_mid = (const float*)d_in[6];
    const float* W_out = (const float*)d_in[7];
    const float* b_out = (const float*)d_in[8];
    const float* W_cls = (const float*)d_in[9];
    const float* b_cls = (const float*)d_in[10];

    const int* src = ei;
    const int* dst = ei + Ee;

    // workspace layout (floats): dis[40000] | norm[640000] | bufA[10.24M] | bufB[10.24M]  ~= 84.6 MB
    float* ws   = (float*)d_ws;
    float* dis  = ws;
    float* norm = ws + 40000;
    float* bufA = ws + 680000;
    float* bufB = ws + 10920000;

    float* out     = (float*)d_out;
    float* ge_out  = out + (size_t)Nn * OUTF;            // 64*128
    float* lg_out  = ge_out + Gg * OUTF;                 // 64*2

    const int nBlkN = (Nn + 255) / 256;   // 157
    const int nBlkE = (Ee + 255) / 256;   // 2500

    // degrees + norms
    k_init_deg<<<nBlkN, 256, 0, stream>>>(dis);
    k_deg<<<nBlkE, 256, 0, stream>>>(dst, dis);
    k_rsqrt<<<nBlkN, 256, 0, stream>>>(dis);
    k_norm<<<nBlkE, 256, 0, stream>>>(src, dst, dis, norm);

    // ---- layer 1: h1 = x @ W_in ; propagate ; +self +bias ; relu ----
    k_gemm<<<dim3(Nn / 64, Hh / 64), 256, 0, stream>>>(x, W_in, bufA, Nn, Hh, INF);
    hipMemsetAsync(bufB, 0, (size_t)Nn * Hh * sizeof(float), stream);
    k_scatter<6><<<(Ee << 6) / 256, 256, 0, stream>>>(src, dst, norm, bufA, bufB);
    k_finalize<6, true><<<(Nn << 6) / 256, 256, 0, stream>>>(bufB, bufA, dis, b_in, bufB);

    // ---- layer 2: h2 = h1p @ W_mid ; propagate ; relu ----
    k_gemm<<<dim3(Nn / 64, Hh / 64), 256, 0, stream>>>(bufB, W_mid, bufA, Nn, Hh, Hh);
    hipMemsetAsync(bufB, 0, (size_t)Nn * Hh * sizeof(float), stream);
    k_scatter<6><<<(Ee << 6) / 256, 256, 0, stream>>>(src, dst, norm, bufA, bufB);
    k_finalize<6, true><<<(Nn << 6) / 256, 256, 0, stream>>>(bufB, bufA, dis, b_mid, bufB);

    // ---- layer 3: h3 = h2p @ W_out ; propagate ; no relu -> node embeddings in d_out ----
    k_gemm<<<dim3(Nn / 64, OUTF / 64), 256, 0, stream>>>(bufB, W_out, bufA, Nn, OUTF, Hh);
    hipMemsetAsync(out, 0, (size_t)Nn * OUTF * sizeof(float), stream);
    k_scatter<5><<<(Ee << 5) / 256, 256, 0, stream>>>(src, dst, norm, bufA, out);
    k_finalize<5, false><<<(Nn << 5) / 256, 256, 0, stream>>>(out, bufA, dis, b_out, out);

    // ---- pooling + classifier ----
    k_pool<<<Gg, 128, 0, stream>>>(out, batch, ge_out);
    k_logits<<<1, 128, 0, stream>>>(ge_out, W_cls, b_cls, lg_out);
}

// Round 2
// 729.717 us; speedup vs baseline: 8.0644x; 8.0644x over previous
//
#include <hip/hip_runtime.h>
#include <hip/hip_bf16.h>

// Problem constants (from reference)
#define Nn   40000
#define Ee   640000
#define Gg   64
#define INF  128
#define Hh   256
#define OUTF 128

#define NBLK_N 157   // ceil(40000/256)

// ---------------- degree histogram ----------------
__global__ __launch_bounds__(256) void k_count(const int* __restrict__ dst, int* __restrict__ cnt) {
    int e = blockIdx.x * 256 + threadIdx.x;
    if (e < Ee) atomicAdd(&cnt[dst[e]], 1);
}

__global__ __launch_bounds__(256) void k_dis(const int* __restrict__ cnt, float* __restrict__ dis) {
    int i = blockIdx.x * 256 + threadIdx.x;
    if (i < Nn) dis[i] = rsqrtf((float)cnt[i] + 1.0f);
}

// ---------------- two-level exclusive scan: cnt[40000] -> offs[40001] ----------------
__global__ __launch_bounds__(256)
void k_scan1(const int* __restrict__ cnt, int* __restrict__ offs, int* __restrict__ partial) {
    __shared__ int sm[256];
    int i = blockIdx.x * 256 + threadIdx.x;
    int v = (i < Nn) ? cnt[i] : 0;
    sm[threadIdx.x] = v;
    __syncthreads();
#pragma unroll
    for (int d = 1; d < 256; d <<= 1) {
        int t = (threadIdx.x >= d) ? sm[threadIdx.x - d] : 0;
        __syncthreads();
        sm[threadIdx.x] += t;
        __syncthreads();
    }
    if (i < Nn) offs[i] = sm[threadIdx.x] - v;     // exclusive within block
    if (threadIdx.x == 255) partial[blockIdx.x] = sm[255];
}

__global__ __launch_bounds__(256)
void k_scan2(int* __restrict__ partial) {
    __shared__ int sm[256];
    int v = (threadIdx.x < NBLK_N) ? partial[threadIdx.x] : 0;
    sm[threadIdx.x] = v;
    __syncthreads();
#pragma unroll
    for (int d = 1; d < 256; d <<= 1) {
        int t = (threadIdx.x >= d) ? sm[threadIdx.x - d] : 0;
        __syncthreads();
        sm[threadIdx.x] += t;
        __syncthreads();
    }
    if (threadIdx.x < NBLK_N) partial[threadIdx.x] = sm[threadIdx.x] - v;   // exclusive
}

__global__ __launch_bounds__(256)
void k_scan3(int* __restrict__ offs, const int* __restrict__ partial) {
    int i = blockIdx.x * 256 + threadIdx.x;
    if (i < Nn) offs[i] += partial[blockIdx.x];
    if (i == 0) offs[Nn] = Ee;
}

// ---------------- CSR fill: bucket src ids by dst ----------------
__global__ __launch_bounds__(256)
void k_fill(const int* __restrict__ src, const int* __restrict__ dst,
            const int* __restrict__ offs, int* __restrict__ cursor,
            unsigned short* __restrict__ src_sorted) {
    int e = blockIdx.x * 256 + threadIdx.x;
    if (e >= Ee) return;
    int d = dst[e];
    int pos = offs[d] + atomicAdd(&cursor[d], 1);
    src_sorted[pos] = (unsigned short)src[e];
}

// ---------------- fp32 tiled GEMM: C[M,N] = A[M,K] @ B[K,N] ----------------
// 64x64 tile, 256 threads, 4x4 micro-tile, BK=16. M%64==0, N%64==0, K%16==0.
__global__ __launch_bounds__(256)
void k_gemm(const float* __restrict__ A, const float* __restrict__ B,
            float* __restrict__ C, int M, int N, int K) {
    __shared__ float As[16][68];
    __shared__ float Bs[16][68];
    const int tid = threadIdx.x;
    const int tx = tid & 15, ty = tid >> 4;
    const int tx4 = tx * 4, ty4 = ty * 4;
    const int rowBase = blockIdx.x * 64;
    const int colBase = blockIdx.y * 64;

    const int arow = tid >> 2;
    const int akc  = (tid & 3) * 4;
    const int brow = tid >> 4;
    const int bcol = (tid & 15) * 4;

    float acc[4][4] = {};

    for (int k0 = 0; k0 < K; k0 += 16) {
        float4 av = *(const float4*)&A[(size_t)(rowBase + arow) * K + k0 + akc];
        float4 bv = *(const float4*)&B[(size_t)(k0 + brow) * N + colBase + bcol];
        __syncthreads();
        As[akc + 0][arow] = av.x;
        As[akc + 1][arow] = av.y;
        As[akc + 2][arow] = av.z;
        As[akc + 3][arow] = av.w;
        *(float4*)&Bs[brow][bcol] = bv;
        __syncthreads();
#pragma unroll
        for (int kk = 0; kk < 16; ++kk) {
            float4 a = *(const float4*)&As[kk][ty4];
            float4 b = *(const float4*)&Bs[kk][tx4];
            acc[0][0] += a.x * b.x; acc[0][1] += a.x * b.y; acc[0][2] += a.x * b.z; acc[0][3] += a.x * b.w;
            acc[1][0] += a.y * b.x; acc[1][1] += a.y * b.y; acc[1][2] += a.y * b.z; acc[1][3] += a.y * b.w;
            acc[2][0] += a.z * b.x; acc[2][1] += a.z * b.y; acc[2][2] += a.z * b.z; acc[2][3] += a.z * b.w;
            acc[3][0] += a.w * b.x; acc[3][1] += a.w * b.y; acc[3][2] += a.w * b.z; acc[3][3] += a.w * b.w;
        }
    }
#pragma unroll
    for (int i = 0; i < 4; ++i) {
        float4 r = make_float4(acc[i][0], acc[i][1], acc[i][2], acc[i][3]);
        *(float4*)&C[(size_t)(rowBase + ty4 + i) * N + colBase + tx4] = r;
    }
}

// ---------------- CSR gather + self-loop + bias (+ReLU), one wave per dst node ----------------
template <int HH, bool RELU>
__global__ __launch_bounds__(256)
void k_gather(const int* __restrict__ offs, const unsigned short* __restrict__ srcs,
              const float* __restrict__ dis, const float* __restrict__ h,
              const float* __restrict__ bias, float* __restrict__ out) {
    constexpr int V = HH / 64;   // floats per lane: 4 (H=256) or 2 (H=128)
    int n = blockIdx.x * 4 + (threadIdx.x >> 6);
    if (n >= Nn) return;
    int lane = threadIdx.x & 63;
    int col = lane * V;
    const float dn = dis[n];
    float acc[V] = {};
    int b = offs[n], e = offs[n + 1];
    int i = b;
    // 2x unrolled edge loop for MLP
    for (; i + 1 < e; i += 2) {
        int s0 = srcs[i], s1 = srcs[i + 1];
        float w0 = dis[s0] * dn, w1 = dis[s1] * dn;
        const float* p0 = h + (size_t)s0 * HH + col;
        const float* p1 = h + (size_t)s1 * HH + col;
        if constexpr (V == 4) {
            float4 v0 = *(const float4*)p0;
            float4 v1 = *(const float4*)p1;
            acc[0] += w0 * v0.x; acc[1] += w0 * v0.y; acc[2] += w0 * v0.z; acc[3] += w0 * v0.w;
            acc[0] += w1 * v1.x; acc[1] += w1 * v1.y; acc[2] += w1 * v1.z; acc[3] += w1 * v1.w;
        } else {
            float2 v0 = *(const float2*)p0;
            float2 v1 = *(const float2*)p1;
            acc[0] += w0 * v0.x; acc[1] += w0 * v0.y;
            acc[0] += w1 * v1.x; acc[1] += w1 * v1.y;
        }
    }
    if (i < e) {
        int s0 = srcs[i];
        float w0 = dis[s0] * dn;
        const float* p0 = h + (size_t)s0 * HH + col;
        if constexpr (V == 4) {
            float4 v0 = *(const float4*)p0;
            acc[0] += w0 * v0.x; acc[1] += w0 * v0.y; acc[2] += w0 * v0.z; acc[3] += w0 * v0.w;
        } else {
            float2 v0 = *(const float2*)p0;
            acc[0] += w0 * v0.x; acc[1] += w0 * v0.y;
        }
    }
    // self-loop + bias (+relu)
    float s2 = dn * dn;
    const float* hp = h + (size_t)n * HH + col;
    float* op = out + (size_t)n * HH + col;
    if constexpr (V == 4) {
        float4 hv = *(const float4*)hp;
        float4 bv = *(const float4*)&bias[col];
        float4 r;
        r.x = acc[0] + s2 * hv.x + bv.x;
        r.y = acc[1] + s2 * hv.y + bv.y;
        r.z = acc[2] + s2 * hv.z + bv.z;
        r.w = acc[3] + s2 * hv.w + bv.w;
        if (RELU) {
            r.x = fmaxf(r.x, 0.0f); r.y = fmaxf(r.y, 0.0f);
            r.z = fmaxf(r.z, 0.0f); r.w = fmaxf(r.w, 0.0f);
        }
        *(float4*)op = r;
    } else {
        float2 hv = *(const float2*)hp;
        float2 bv = *(const float2*)&bias[col];
        float2 r;
        r.x = acc[0] + s2 * hv.x + bv.x;
        r.y = acc[1] + s2 * hv.y + bv.y;
        if (RELU) { r.x = fmaxf(r.x, 0.0f); r.y = fmaxf(r.y, 0.0f); }
        *(float2*)op = r;
    }
}

// ---------------- global mean pool per graph (batch sorted -> binary search) ----------------
__global__ __launch_bounds__(128)
void k_pool(const float* __restrict__ emb, const int* __restrict__ batch,
            float* __restrict__ ge) {
    int g = blockIdx.x;
    int f = threadIdx.x;
    int lo = 0, hi = Nn;
    while (lo < hi) { int mid = (lo + hi) >> 1; if (batch[mid] < g) lo = mid + 1; else hi = mid; }
    int start = lo;
    hi = Nn;
    while (lo < hi) { int mid = (lo + hi) >> 1; if (batch[mid] < g + 1) lo = mid + 1; else hi = mid; }
    int end = lo;
    float s = 0.0f;
    for (int n = start; n < end; ++n) s += emb[(size_t)n * OUTF + f];
    float cnt = (float)(end - start);
    ge[g * OUTF + f] = s / fmaxf(cnt, 1.0f);
}

// ---------------- logits: ge[64,128] @ W_cls[128,2] + b_cls ----------------
__global__ __launch_bounds__(128)
void k_logits(const float* __restrict__ ge, const float* __restrict__ Wc,
              const float* __restrict__ bc, float* __restrict__ out) {
    int t = threadIdx.x;
    int g = t >> 1, c = t & 1;
    float s = bc[c];
    for (int k = 0; k < 128; ++k) s += ge[g * 128 + k] * Wc[k * 2 + c];
    out[t] = s;
}

extern "C" void kernel_launch(void* const* d_in, const int* in_sizes, int n_in,
                              void* d_out, int out_size, void* d_ws, size_t ws_size,
                              hipStream_t stream) {
    const float* x     = (const float*)d_in[0];
    const int*   ei    = (const int*)d_in[1];
    const int*   batch = (const int*)d_in[2];
    const float* W_in  = (const float*)d_in[3];
    const float* b_in  = (const float*)d_in[4];
    const float* W_mid = (const float*)d_in[5];
    const float* b_mid = (const float*)d_in[6];
    const float* W_out = (const float*)d_in[7];
    const float* b_out = (const float*)d_in[8];
    const float* W_cls = (const float*)d_in[9];
    const float* b_cls = (const float*)d_in[10];

    const int* src = ei;
    const int* dst = ei + Ee;

    // workspace layout (4B units):
    // dis[40000] | cnt/cursor[40000] | offs[40001->40064] | partial[160->192] |
    // src_sorted ushort[640000] (=320000 floats) | bufA[10.24M] | bufB[10.24M]
    float* ws = (float*)d_ws;
    float* dis  = ws;                                    // 0
    int*   cnt  = (int*)(ws + 40000);                    // 40000
    int*   offs = (int*)(ws + 80000);                    // 80000..120064
    int*   partial = (int*)(ws + 120064);                // 160 entries
    unsigned short* src_sorted = (unsigned short*)(ws + 120256);
    float* bufA = ws + 440256;
    float* bufB = ws + 10680256;
    // end = 20,920,256 floats = 83.7 MB

    float* out    = (float*)d_out;
    float* ge_out = out + (size_t)Nn * OUTF;
    float* lg_out = ge_out + Gg * OUTF;

    const int nBlkE = (Ee + 255) / 256;
    const int nBlkG = (Nn + 3) / 4;

    // ---- CSR build ----
    hipMemsetAsync(cnt, 0, Nn * sizeof(int), stream);
    k_count<<<nBlkE, 256, 0, stream>>>(dst, cnt);
    k_dis<<<NBLK_N, 256, 0, stream>>>(cnt, dis);
    k_scan1<<<NBLK_N, 256, 0, stream>>>(cnt, offs, partial);
    k_scan2<<<1, 256, 0, stream>>>(partial);
    k_scan3<<<NBLK_N, 256, 0, stream>>>(offs, partial);
    hipMemsetAsync(cnt, 0, Nn * sizeof(int), stream);
    k_fill<<<nBlkE, 256, 0, stream>>>(src, dst, offs, cnt, src_sorted);

    // ---- layer 1 ----
    k_gemm<<<dim3(Nn / 64, Hh / 64), 256, 0, stream>>>(x, W_in, bufA, Nn, Hh, INF);
    k_gather<Hh, true><<<nBlkG, 256, 0, stream>>>(offs, src_sorted, dis, bufA, b_in, bufB);

    // ---- layer 2 ----
    k_gemm<<<dim3(Nn / 64, Hh / 64), 256, 0, stream>>>(bufB, W_mid, bufA, Nn, Hh, Hh);
    k_gather<Hh, true><<<nBlkG, 256, 0, stream>>>(offs, src_sorted, dis, bufA, b_mid, bufB);

    // ---- layer 3 -> node embeddings in d_out ----
    k_gemm<<<dim3(Nn / 64, OUTF / 64), 256, 0, stream>>>(bufB, W_out, bufA, Nn, OUTF, Hh);
    k_gather<OUTF, false><<<nBlkG, 256, 0, stream>>>(offs, src_sorted, dis, bufA, b_out, out);

    // ---- pooling + classifier ----
    k_pool<<<Gg, 128, 0, stream>>>(out, batch, ge_out);
    k_logits<<<1, 128, 0, stream>>>(ge_out, W_cls, b_cls, lg_out);
}

// Round 3
// 585.404 us; speedup vs baseline: 10.0524x; 1.2465x over previous
//
#include <hip/hip_runtime.h>
#include <hip/hip_bf16.h>

// Problem constants (from reference)
#define Nn   40000
#define Ee   640000
#define Gg   64
#define INF  128
#define Hh   256
#define OUTF 128

#define NBLK_N 157   // ceil(40000/256)

// ---------------- degree histogram ----------------
__global__ __launch_bounds__(256) void k_count(const int* __restrict__ dst, int* __restrict__ cnt) {
    int e = blockIdx.x * 256 + threadIdx.x;
    if (e < Ee) atomicAdd(&cnt[dst[e]], 1);
}

__global__ __launch_bounds__(256) void k_dis(const int* __restrict__ cnt, float* __restrict__ dis) {
    int i = blockIdx.x * 256 + threadIdx.x;
    if (i < Nn) dis[i] = rsqrtf((float)cnt[i] + 1.0f);
}

// ---------------- two-level exclusive scan: cnt[40000] -> offs[40001] ----------------
__global__ __launch_bounds__(256)
void k_scan1(const int* __restrict__ cnt, int* __restrict__ offs, int* __restrict__ partial) {
    __shared__ int sm[256];
    int i = blockIdx.x * 256 + threadIdx.x;
    int v = (i < Nn) ? cnt[i] : 0;
    sm[threadIdx.x] = v;
    __syncthreads();
#pragma unroll
    for (int d = 1; d < 256; d <<= 1) {
        int t = (threadIdx.x >= d) ? sm[threadIdx.x - d] : 0;
        __syncthreads();
        sm[threadIdx.x] += t;
        __syncthreads();
    }
    if (i < Nn) offs[i] = sm[threadIdx.x] - v;     // exclusive within block
    if (threadIdx.x == 255) partial[blockIdx.x] = sm[255];
}

__global__ __launch_bounds__(256)
void k_scan2(int* __restrict__ partial) {
    __shared__ int sm[256];
    int v = (threadIdx.x < NBLK_N) ? partial[threadIdx.x] : 0;
    sm[threadIdx.x] = v;
    __syncthreads();
#pragma unroll
    for (int d = 1; d < 256; d <<= 1) {
        int t = (threadIdx.x >= d) ? sm[threadIdx.x - d] : 0;
        __syncthreads();
        sm[threadIdx.x] += t;
        __syncthreads();
    }
    if (threadIdx.x < NBLK_N) partial[threadIdx.x] = sm[threadIdx.x] - v;   // exclusive
}

__global__ __launch_bounds__(256)
void k_scan3(int* __restrict__ offs, const int* __restrict__ partial) {
    int i = blockIdx.x * 256 + threadIdx.x;
    if (i < Nn) offs[i] += partial[blockIdx.x];
    if (i == 0) offs[Nn] = Ee;
}

// ---------------- CSR fill: bucket src ids by dst ----------------
__global__ __launch_bounds__(256)
void k_fill(const int* __restrict__ src, const int* __restrict__ dst,
            const int* __restrict__ offs, int* __restrict__ cursor,
            unsigned short* __restrict__ src_sorted) {
    int e = blockIdx.x * 256 + threadIdx.x;
    if (e >= Ee) return;
    int d = dst[e];
    int pos = offs[d] + atomicAdd(&cursor[d], 1);
    src_sorted[pos] = (unsigned short)src[e];
}

// ---------------- fp32 tiled GEMM: C[M,N] = A[M,K] @ B[K,N] ----------------
__global__ __launch_bounds__(256)
void k_gemm(const float* __restrict__ A, const float* __restrict__ B,
            float* __restrict__ C, int M, int N, int K) {
    __shared__ float As[16][68];
    __shared__ float Bs[16][68];
    const int tid = threadIdx.x;
    const int tx = tid & 15, ty = tid >> 4;
    const int tx4 = tx * 4, ty4 = ty * 4;
    const int rowBase = blockIdx.x * 64;
    const int colBase = blockIdx.y * 64;

    const int arow = tid >> 2;
    const int akc  = (tid & 3) * 4;
    const int brow = tid >> 4;
    const int bcol = (tid & 15) * 4;

    float acc[4][4] = {};

    for (int k0 = 0; k0 < K; k0 += 16) {
        float4 av = *(const float4*)&A[(size_t)(rowBase + arow) * K + k0 + akc];
        float4 bv = *(const float4*)&B[(size_t)(k0 + brow) * N + colBase + bcol];
        __syncthreads();
        As[akc + 0][arow] = av.x;
        As[akc + 1][arow] = av.y;
        As[akc + 2][arow] = av.z;
        As[akc + 3][arow] = av.w;
        *(float4*)&Bs[brow][bcol] = bv;
        __syncthreads();
#pragma unroll
        for (int kk = 0; kk < 16; ++kk) {
            float4 a = *(const float4*)&As[kk][ty4];
            float4 b = *(const float4*)&Bs[kk][tx4];
            acc[0][0] += a.x * b.x; acc[0][1] += a.x * b.y; acc[0][2] += a.x * b.z; acc[0][3] += a.x * b.w;
            acc[1][0] += a.y * b.x; acc[1][1] += a.y * b.y; acc[1][2] += a.y * b.z; acc[1][3] += a.y * b.w;
            acc[2][0] += a.z * b.x; acc[2][1] += a.z * b.y; acc[2][2] += a.z * b.z; acc[2][3] += a.z * b.w;
            acc[3][0] += a.w * b.x; acc[3][1] += a.w * b.y; acc[3][2] += a.w * b.z; acc[3][3] += a.w * b.w;
        }
    }
#pragma unroll
    for (int i = 0; i < 4; ++i) {
        float4 r = make_float4(acc[i][0], acc[i][1], acc[i][2], acc[i][3]);
        *(float4*)&C[(size_t)(rowBase + ty4 + i) * N + colBase + tx4] = r;
    }
}

// ---------------- CSR gather + self-loop + bias (+ReLU), one wave per dst node ----------------
template <int HH, bool RELU>
__global__ __launch_bounds__(256)
void k_gather(const int* __restrict__ offs, const unsigned short* __restrict__ srcs,
              const float* __restrict__ dis, const float* __restrict__ h,
              const float* __restrict__ bias, float* __restrict__ out) {
    constexpr int V = HH / 64;   // floats per lane: 4 (H=256) or 2 (H=128)
    int n = blockIdx.x * 4 + (threadIdx.x >> 6);
    if (n >= Nn) return;
    int lane = threadIdx.x & 63;
    int col = lane * V;
    const float dn = dis[n];
    float acc[V] = {};
    int b = offs[n], e = offs[n + 1];
    int i = b;
    for (; i + 1 < e; i += 2) {
        int s0 = srcs[i], s1 = srcs[i + 1];
        float w0 = dis[s0] * dn, w1 = dis[s1] * dn;
        const float* p0 = h + (size_t)s0 * HH + col;
        const float* p1 = h + (size_t)s1 * HH + col;
        if constexpr (V == 4) {
            float4 v0 = *(const float4*)p0;
            float4 v1 = *(const float4*)p1;
            acc[0] += w0 * v0.x; acc[1] += w0 * v0.y; acc[2] += w0 * v0.z; acc[3] += w0 * v0.w;
            acc[0] += w1 * v1.x; acc[1] += w1 * v1.y; acc[2] += w1 * v1.z; acc[3] += w1 * v1.w;
        } else {
            float2 v0 = *(const float2*)p0;
            float2 v1 = *(const float2*)p1;
            acc[0] += w0 * v0.x; acc[1] += w0 * v0.y;
            acc[0] += w1 * v1.x; acc[1] += w1 * v1.y;
        }
    }
    if (i < e) {
        int s0 = srcs[i];
        float w0 = dis[s0] * dn;
        const float* p0 = h + (size_t)s0 * HH + col;
        if constexpr (V == 4) {
            float4 v0 = *(const float4*)p0;
            acc[0] += w0 * v0.x; acc[1] += w0 * v0.y; acc[2] += w0 * v0.z; acc[3] += w0 * v0.w;
        } else {
            float2 v0 = *(const float2*)p0;
            acc[0] += w0 * v0.x; acc[1] += w0 * v0.y;
        }
    }
    float s2 = dn * dn;
    const float* hp = h + (size_t)n * HH + col;
    float* op = out + (size_t)n * HH + col;
    if constexpr (V == 4) {
        float4 hv = *(const float4*)hp;
        float4 bv = *(const float4*)&bias[col];
        float4 r;
        r.x = acc[0] + s2 * hv.x + bv.x;
        r.y = acc[1] + s2 * hv.y + bv.y;
        r.z = acc[2] + s2 * hv.z + bv.z;
        r.w = acc[3] + s2 * hv.w + bv.w;
        if (RELU) {
            r.x = fmaxf(r.x, 0.0f); r.y = fmaxf(r.y, 0.0f);
            r.z = fmaxf(r.z, 0.0f); r.w = fmaxf(r.w, 0.0f);
        }
        *(float4*)op = r;
    } else {
        float2 hv = *(const float2*)hp;
        float2 bv = *(const float2*)&bias[col];
        float2 r;
        r.x = acc[0] + s2 * hv.x + bv.x;
        r.y = acc[1] + s2 * hv.y + bv.y;
        if (RELU) { r.x = fmaxf(r.x, 0.0f); r.y = fmaxf(r.y, 0.0f); }
        *(float2*)op = r;
    }
}

// ---------------- pool phase 1: chunked segment-aware accumulation ----------------
// 625 blocks x 256 threads; block b reduces nodes [64b, 64b+64).
// Thread t: sub-row = t>>6 (stride 4 over nodes), feature pair = (t&63)*2.
// batch sorted => per-thread register accumulate until graph id changes, then atomic flush.
__global__ __launch_bounds__(256)
void k_pool_accum(const float* __restrict__ emb, const int* __restrict__ batch,
                  float* __restrict__ ge_accum) {
    int n0 = blockIdx.x * 64;
    int nend = min(n0 + 64, Nn);
    int sub = threadIdx.x >> 6;
    int col = (threadIdx.x & 63) * 2;
    float ax = 0.0f, ay = 0.0f;
    int cur_g = -1;
    for (int n = n0 + sub; n < nend; n += 4) {
        int g = batch[n];
        if (g != cur_g) {
            if (cur_g >= 0) {
                unsafeAtomicAdd(&ge_accum[cur_g * OUTF + col], ax);
                unsafeAtomicAdd(&ge_accum[cur_g * OUTF + col + 1], ay);
            }
            cur_g = g; ax = 0.0f; ay = 0.0f;
        }
        float2 v = *(const float2*)&emb[(size_t)n * OUTF + col];
        ax += v.x; ay += v.y;
    }
    if (cur_g >= 0) {
        unsafeAtomicAdd(&ge_accum[cur_g * OUTF + col], ax);
        unsafeAtomicAdd(&ge_accum[cur_g * OUTF + col + 1], ay);
    }
}

// ---------------- pool phase 2: divide by segment count ----------------
__global__ __launch_bounds__(256)
void k_pool_div(const float* __restrict__ ge_accum, const int* __restrict__ batch,
                float* __restrict__ ge) {
    int idx = blockIdx.x * 256 + threadIdx.x;   // 0..8191
    if (idx >= Gg * OUTF) return;
    int g = idx >> 7;
    int lo = 0, hi = Nn;
    while (lo < hi) { int mid = (lo + hi) >> 1; if (batch[mid] < g) lo = mid + 1; else hi = mid; }
    int start = lo;
    hi = Nn;
    while (lo < hi) { int mid = (lo + hi) >> 1; if (batch[mid] < g + 1) lo = mid + 1; else hi = mid; }
    float cnt = (float)(lo - start);
    ge[idx] = ge_accum[idx] / fmaxf(cnt, 1.0f);
}

// ---------------- logits: ge[64,128] @ W_cls[128,2] + b_cls ----------------
__global__ __launch_bounds__(128)
void k_logits(const float* __restrict__ ge, const float* __restrict__ Wc,
              const float* __restrict__ bc, float* __restrict__ out) {
    int t = threadIdx.x;
    int g = t >> 1, c = t & 1;
    float s = bc[c];
    for (int k = 0; k < 128; ++k) s += ge[g * 128 + k] * Wc[k * 2 + c];
    out[t] = s;
}

extern "C" void kernel_launch(void* const* d_in, const int* in_sizes, int n_in,
                              void* d_out, int out_size, void* d_ws, size_t ws_size,
                              hipStream_t stream) {
    const float* x     = (const float*)d_in[0];
    const int*   ei    = (const int*)d_in[1];
    const int*   batch = (const int*)d_in[2];
    const float* W_in  = (const float*)d_in[3];
    const float* b_in  = (const float*)d_in[4];
    const float* W_mid = (const float*)d_in[5];
    const float* b_mid = (const float*)d_in[6];
    const float* W_out = (const float*)d_in[7];
    const float* b_out = (const float*)d_in[8];
    const float* W_cls = (const float*)d_in[9];
    const float* b_cls = (const float*)d_in[10];

    const int* src = ei;
    const int* dst = ei + Ee;

    // workspace layout (4B units):
    // dis[40000] | cnt/cursor[40000] | offs[40064] | partial[192] | ge_accum[8192] |
    // src_sorted ushort[640000] (=320000 floats) | bufA[10.24M] | bufB[10.24M]
    float* ws = (float*)d_ws;
    float* dis     = ws;                           // 0
    int*   cnt     = (int*)(ws + 40000);           // 40000
    int*   offs    = (int*)(ws + 80000);           // 80000..120064
    int*   partial = (int*)(ws + 120064);          // 192
    float* ge_accum = ws + 120256;                 // 8192
    unsigned short* src_sorted = (unsigned short*)(ws + 128448);
    float* bufA = ws + 448448;
    float* bufB = ws + 10688448;
    // end = 20,928,448 floats = 83.7 MB

    float* out    = (float*)d_out;
    float* ge_out = out + (size_t)Nn * OUTF;
    float* lg_out = ge_out + Gg * OUTF;

    const int nBlkE = (Ee + 255) / 256;
    const int nBlkG = (Nn + 3) / 4;

    // ---- CSR build ----
    hipMemsetAsync(cnt, 0, Nn * sizeof(int), stream);
    k_count<<<nBlkE, 256, 0, stream>>>(dst, cnt);
    k_dis<<<NBLK_N, 256, 0, stream>>>(cnt, dis);
    k_scan1<<<NBLK_N, 256, 0, stream>>>(cnt, offs, partial);
    k_scan2<<<1, 256, 0, stream>>>(partial);
    k_scan3<<<NBLK_N, 256, 0, stream>>>(offs, partial);
    hipMemsetAsync(cnt, 0, Nn * sizeof(int), stream);
    k_fill<<<nBlkE, 256, 0, stream>>>(src, dst, offs, cnt, src_sorted);

    // ---- layer 1 ----
    k_gemm<<<dim3(Nn / 64, Hh / 64), 256, 0, stream>>>(x, W_in, bufA, Nn, Hh, INF);
    k_gather<Hh, true><<<nBlkG, 256, 0, stream>>>(offs, src_sorted, dis, bufA, b_in, bufB);

    // ---- layer 2 ----
    k_gemm<<<dim3(Nn / 64, Hh / 64), 256, 0, stream>>>(bufB, W_mid, bufA, Nn, Hh, Hh);
    k_gather<Hh, true><<<nBlkG, 256, 0, stream>>>(offs, src_sorted, dis, bufA, b_mid, bufB);

    // ---- layer 3 -> node embeddings in d_out ----
    k_gemm<<<dim3(Nn / 64, OUTF / 64), 256, 0, stream>>>(bufB, W_out, bufA, Nn, OUTF, Hh);
    k_gather<OUTF, false><<<nBlkG, 256, 0, stream>>>(offs, src_sorted, dis, bufA, b_out, out);

    // ---- pooling + classifier ----
    hipMemsetAsync(ge_accum, 0, Gg * OUTF * sizeof(float), stream);
    k_pool_accum<<<(Nn + 63) / 64, 256, 0, stream>>>(out, batch, ge_accum);
    k_pool_div<<<(Gg * OUTF + 255) / 256, 256, 0, stream>>>(ge_accum, batch, ge_out);
    k_logits<<<1, 128, 0, stream>>>(ge_out, W_cls, b_cls, lg_out);
}